// Round 1
// baseline (2225.012 us; speedup 1.0000x reference)
//
#include <hip/hip_runtime.h>

// HeteroGNN on MI355X — round 1: correct fp32 implementation.
// Structure:
//   1. histogram cites-dst degrees + writes-dst counts
//   2. exclusive scan (3-kernel) -> CSR row offsets for both edge types
//   3. atomic-ticket CSR fill (src lists sorted by dst)
//   4. node_prep: dinv = rsqrt(deg+1); mean_author via writes-CSR gather (layer-invariant)
//   5. per layer: GEMM g = (x@W)*dinv[row]; GEMM r = x@Wr + mean@Wl + b + bl
//                 gather: p[d] = relu(dinv[d]*(sum_nbr g[s] + g[d]) + r[d])
//   6. out = p2 @ lin_W + lin_b  (N=349)

#define DP   256
#define DA   128
#define HIDN 256
#define DOUT 349

// ---------------- histogram ----------------
__global__ void hist_kernel(const int* __restrict__ c_dst, const int* __restrict__ w_dst,
                            int* __restrict__ deg_c, int* __restrict__ cnt_w, int e) {
  int i = blockIdx.x * blockDim.x + threadIdx.x;
  if (i < e) {
    atomicAdd(&deg_c[c_dst[i]], 1);
    atomicAdd(&cnt_w[w_dst[i]], 1);
  }
}

// ---------------- exclusive scan (2048 per block) ----------------
#define SCAN_TPB 256
#define SCAN_VPT 8
#define SCAN_TILE 2048

__global__ void scan_local(const int* __restrict__ in, int* __restrict__ out,
                           int* __restrict__ bsum, int n) {
  __shared__ int sdata[SCAN_TPB];
  int t = threadIdx.x;
  int base = blockIdx.x * SCAN_TILE + t * SCAN_VPT;
  int v[SCAN_VPT];
  int sum = 0;
#pragma unroll
  for (int j = 0; j < SCAN_VPT; ++j) {
    int idx = base + j;
    v[j] = (idx < n) ? in[idx] : 0;
    sum += v[j];
  }
  sdata[t] = sum;
  __syncthreads();
  for (int off = 1; off < SCAN_TPB; off <<= 1) {
    int x = (t >= off) ? sdata[t - off] : 0;
    __syncthreads();
    sdata[t] += x;
    __syncthreads();
  }
  int prefix = sdata[t] - sum;  // exclusive prefix of this thread within block
  if (t == SCAN_TPB - 1) bsum[blockIdx.x] = sdata[t];
  int run = prefix;
#pragma unroll
  for (int j = 0; j < SCAN_VPT; ++j) {
    int idx = base + j;
    if (idx < n) out[idx] = run;
    run += v[j];
  }
}

__global__ void scan_spine(int* __restrict__ bsum, int nb) {
  __shared__ int sdata[256];
  int t = threadIdx.x;
  int v = (t < nb) ? bsum[t] : 0;
  sdata[t] = v;
  __syncthreads();
  for (int off = 1; off < 256; off <<= 1) {
    int x = (t >= off) ? sdata[t - off] : 0;
    __syncthreads();
    sdata[t] += x;
    __syncthreads();
  }
  if (t < nb) bsum[t] = sdata[t] - v;  // exclusive
}

__global__ void scan_add(int* __restrict__ out, const int* __restrict__ bsum, int n) {
  int add = bsum[blockIdx.x];
  int base = blockIdx.x * SCAN_TILE + threadIdx.x * SCAN_VPT;
#pragma unroll
  for (int j = 0; j < SCAN_VPT; ++j) {
    int idx = base + j;
    if (idx < n) out[idx] += add;
  }
}

// ---------------- CSR fill (atomic ticket) ----------------
__global__ void fill_csr(const int* __restrict__ c_src, const int* __restrict__ c_dst,
                         const int* __restrict__ w_src, const int* __restrict__ w_dst,
                         int* __restrict__ cur_c, int* __restrict__ cur_w,
                         int* __restrict__ c_sorted, int* __restrict__ w_sorted, int e) {
  int i = blockIdx.x * blockDim.x + threadIdx.x;
  if (i < e) {
    int d = c_dst[i];
    int pos = atomicAdd(&cur_c[d], 1);
    c_sorted[pos] = c_src[i];
    int d2 = w_dst[i];
    int pos2 = atomicAdd(&cur_w[d2], 1);
    w_sorted[pos2] = w_src[i];
  }
}

// ---------------- node prep: dinv + author-mean (wave per node) ----------------
__global__ void node_prep(const float* __restrict__ x_author,
                          const int* __restrict__ w_off, const int* __restrict__ w_cnt,
                          const int* __restrict__ w_sorted,
                          const int* __restrict__ deg_c,
                          float* __restrict__ mean, float* __restrict__ dinv, int n) {
  int wave = (blockIdx.x * blockDim.x + threadIdx.x) >> 6;
  int lane = threadIdx.x & 63;
  if (wave >= n) return;
  int d = wave;
  int start = w_off[d];
  int cnt = w_cnt[d];
  float ax = 0.f, ay = 0.f;
  const float2* xa = (const float2*)x_author;
  for (int j = 0; j < cnt; ++j) {
    int s = w_sorted[start + j];
    float2 v = xa[(size_t)s * (DA / 2) + lane];
    ax += v.x;
    ay += v.y;
  }
  float inv = 1.0f / (float)((cnt > 0) ? cnt : 1);
  float2* m = (float2*)mean;
  float2 o; o.x = ax * inv; o.y = ay * inv;
  m[(size_t)d * (DA / 2) + lane] = o;
  if (lane == 0) dinv[d] = rsqrtf((float)(deg_c[d] + 1));
}

// ---------------- GCN gather + combine + relu (wave per node) ----------------
__global__ void gcn_gather(const float* __restrict__ g, const float* __restrict__ r,
                           const float* __restrict__ dinv,
                           const int* __restrict__ c_off, const int* __restrict__ c_cnt,
                           const int* __restrict__ c_sorted,
                           float* __restrict__ p, int n) {
  int wave = (blockIdx.x * blockDim.x + threadIdx.x) >> 6;
  int lane = threadIdx.x & 63;
  if (wave >= n) return;
  int d = wave;
  int start = c_off[d];
  int cnt = c_cnt[d];
  float a0 = 0.f, a1 = 0.f, a2 = 0.f, a3 = 0.f;
  const float4* G = (const float4*)g;
  for (int j = 0; j < cnt; ++j) {
    int s = c_sorted[start + j];
    float4 v = G[(size_t)s * (HIDN / 4) + lane];
    a0 += v.x; a1 += v.y; a2 += v.z; a3 += v.w;
  }
  float4 self = G[(size_t)d * (HIDN / 4) + lane];
  float sc = dinv[d];
  const float4* R = (const float4*)r;
  float4 rv = R[(size_t)d * (HIDN / 4) + lane];
  float4 o;
  o.x = fmaxf(fmaf(a0 + self.x, sc, rv.x), 0.f);
  o.y = fmaxf(fmaf(a1 + self.y, sc, rv.y), 0.f);
  o.z = fmaxf(fmaf(a2 + self.z, sc, rv.z), 0.f);
  o.w = fmaxf(fmaf(a3 + self.w, sc, rv.w), 0.f);
  ((float4*)p)[(size_t)d * (HIDN / 4) + lane] = o;
}

// ---------------- fp32 tiled GEMM: C = A1@B1 (+ A2@B2) (+bias1+bias2) (*rowscale) --------
#define GBM 64
#define GBN 64
#define GBK 32

__global__ __launch_bounds__(256) void gemm_fused(
    const float* __restrict__ A1, const float* __restrict__ B1, int K1,
    const float* __restrict__ A2, const float* __restrict__ B2, int K2,
    const float* __restrict__ bias1, const float* __restrict__ bias2,
    const float* __restrict__ rowscale,
    float* __restrict__ C, int M, int N) {
  __shared__ float As[GBK][GBM + 4];
  __shared__ float Bs[GBK][GBN + 4];
  int t = threadIdx.x;
  int ty = t >> 4, tx = t & 15;
  int gm = blockIdx.x * GBM;
  int gn = blockIdx.y * GBN;
  float acc[4][4] = {};

  for (int pass = 0; pass < 2; ++pass) {
    const float* A = pass ? A2 : A1;
    const float* B = pass ? B2 : B1;
    int K = pass ? K2 : K1;
    if (A == nullptr) continue;
    for (int k0 = 0; k0 < K; k0 += GBK) {
      __syncthreads();
      // A tile: 64 rows x 32 k  (each thread: 8 consecutive k of one row)
      {
        int arow = t >> 2;
        int acol = (t & 3) << 3;
        float av[8];
        if (gm + arow < M) {
          const float* ap = A + (size_t)(gm + arow) * K + (k0 + acol);
          float4 v0 = *(const float4*)ap;
          float4 v1 = *(const float4*)(ap + 4);
          av[0] = v0.x; av[1] = v0.y; av[2] = v0.z; av[3] = v0.w;
          av[4] = v1.x; av[5] = v1.y; av[6] = v1.z; av[7] = v1.w;
        } else {
#pragma unroll
          for (int j = 0; j < 8; ++j) av[j] = 0.f;
        }
#pragma unroll
        for (int j = 0; j < 8; ++j) As[acol + j][arow] = av[j];
      }
      // B tile: 32 k x 64 n
      {
        int brow = t >> 3;
        int bcol = (t & 7) << 3;
        const float* bp = B + (size_t)(k0 + brow) * N + gn + bcol;
#pragma unroll
        for (int j = 0; j < 8; ++j) {
          int col = gn + bcol + j;
          Bs[brow][bcol + j] = (col < N) ? bp[j] : 0.f;
        }
      }
      __syncthreads();
#pragma unroll
      for (int kk = 0; kk < GBK; ++kk) {
        float4 a = *(const float4*)&As[kk][ty << 2];
        float4 b = *(const float4*)&Bs[kk][tx << 2];
        float avv[4] = {a.x, a.y, a.z, a.w};
        float bvv[4] = {b.x, b.y, b.z, b.w};
#pragma unroll
        for (int i = 0; i < 4; ++i)
#pragma unroll
          for (int j = 0; j < 4; ++j)
            acc[i][j] = fmaf(avv[i], bvv[j], acc[i][j]);
      }
    }
  }

#pragma unroll
  for (int i = 0; i < 4; ++i) {
    int row = gm + (ty << 2) + i;
    if (row >= M) continue;
    float rs = rowscale ? rowscale[row] : 1.0f;
#pragma unroll
    for (int j = 0; j < 4; ++j) {
      int col = gn + (tx << 2) + j;
      if (col >= N) continue;
      float v = acc[i][j] * rs;
      if (bias1) v += bias1[col];
      if (bias2) v += bias2[col];
      C[(size_t)row * N + col] = v;
    }
  }
}

// ---------------- launch ----------------
static inline size_t align_up(size_t x) { return (x + 255) & ~(size_t)255; }

extern "C" void kernel_launch(void* const* d_in, const int* in_sizes, int n_in,
                              void* d_out, int out_size, void* d_ws, size_t ws_size,
                              hipStream_t stream) {
  const float* x_paper  = (const float*)d_in[0];
  const float* x_author = (const float*)d_in[1];
  const int*   cites    = (const int*)d_in[2];
  const int*   w_src    = (const int*)d_in[3];
  const int*   w_dst    = (const int*)d_in[4];
  const float* W1  = (const float*)d_in[5];
  const float* b1  = (const float*)d_in[6];
  const float* Wl1 = (const float*)d_in[7];
  const float* bl1 = (const float*)d_in[8];
  const float* Wr1 = (const float*)d_in[9];
  const float* W2  = (const float*)d_in[10];
  const float* b2  = (const float*)d_in[11];
  const float* Wl2 = (const float*)d_in[12];
  const float* bl2 = (const float*)d_in[13];
  const float* Wr2 = (const float*)d_in[14];
  const float* linW = (const float*)d_in[15];
  const float* linb = (const float*)d_in[16];
  float* out = (float*)d_out;

  const int N = in_sizes[0] / DP;     // 100000 papers
  const int E = in_sizes[3];          // 1000000 edges
  const int* c_src = cites;
  const int* c_dst = cites + E;

  // workspace carve-up
  char* w = (char*)d_ws;
  size_t off = 0;
  auto alloc = [&](size_t bytes) -> void* {
    void* p = w + off;
    off = align_up(off + bytes);
    return p;
  };
  int* deg_c      = (int*)alloc((size_t)N * 4);
  int* cnt_w      = (int*)alloc((size_t)N * 4);
  int* cites_off  = (int*)alloc((size_t)N * 4);
  int* writes_off = (int*)alloc((size_t)N * 4);
  int* cur_c      = (int*)alloc((size_t)N * 4);
  int* cur_w      = (int*)alloc((size_t)N * 4);
  int* bsumA      = (int*)alloc(256 * 4);
  int* bsumB      = (int*)alloc(256 * 4);
  int* c_sorted   = (int*)alloc((size_t)E * 4);
  int* w_sorted   = (int*)alloc((size_t)E * 4);
  float* dinv     = (float*)alloc((size_t)N * 4);
  float* meanA    = (float*)alloc((size_t)N * DA * 4);
  float* gbuf     = (float*)alloc((size_t)N * HIDN * 4);
  float* rbuf     = (float*)alloc((size_t)N * HIDN * 4);
  float* pbuf     = (float*)alloc((size_t)N * HIDN * 4);
  (void)ws_size; (void)n_in; (void)out_size;

  hipMemsetAsync(deg_c, 0, (size_t)N * 4, stream);
  hipMemsetAsync(cnt_w, 0, (size_t)N * 4, stream);

  int nbE = (E + 255) / 256;
  hist_kernel<<<nbE, 256, 0, stream>>>(c_dst, w_dst, deg_c, cnt_w, E);

  int nsb = (N + SCAN_TILE - 1) / SCAN_TILE;  // 49
  scan_local<<<nsb, SCAN_TPB, 0, stream>>>(deg_c, cites_off, bsumA, N);
  scan_spine<<<1, 256, 0, stream>>>(bsumA, nsb);
  scan_add<<<nsb, SCAN_TPB, 0, stream>>>(cites_off, bsumA, N);
  scan_local<<<nsb, SCAN_TPB, 0, stream>>>(cnt_w, writes_off, bsumB, N);
  scan_spine<<<1, 256, 0, stream>>>(bsumB, nsb);
  scan_add<<<nsb, SCAN_TPB, 0, stream>>>(writes_off, bsumB, N);

  hipMemcpyAsync(cur_c, cites_off, (size_t)N * 4, hipMemcpyDeviceToDevice, stream);
  hipMemcpyAsync(cur_w, writes_off, (size_t)N * 4, hipMemcpyDeviceToDevice, stream);
  fill_csr<<<nbE, 256, 0, stream>>>(c_src, c_dst, w_src, w_dst, cur_c, cur_w,
                                    c_sorted, w_sorted, E);

  int nbWave = (N * 64 + 255) / 256;  // one wave per node
  node_prep<<<nbWave, 256, 0, stream>>>(x_author, writes_off, cnt_w, w_sorted,
                                        deg_c, meanA, dinv, N);

  dim3 gdim((N + GBM - 1) / GBM, (HIDN + GBN - 1) / GBN);
  // layer 1
  gemm_fused<<<gdim, 256, 0, stream>>>(x_paper, W1, DP, nullptr, nullptr, 0,
                                       nullptr, nullptr, dinv, gbuf, N, HIDN);
  gemm_fused<<<gdim, 256, 0, stream>>>(x_paper, Wr1, DP, meanA, Wl1, DA,
                                       b1, bl1, nullptr, rbuf, N, HIDN);
  gcn_gather<<<nbWave, 256, 0, stream>>>(gbuf, rbuf, dinv, cites_off, deg_c,
                                         c_sorted, pbuf, N);
  // layer 2
  gemm_fused<<<gdim, 256, 0, stream>>>(pbuf, W2, HIDN, nullptr, nullptr, 0,
                                       nullptr, nullptr, dinv, gbuf, N, HIDN);
  gemm_fused<<<gdim, 256, 0, stream>>>(pbuf, Wr2, HIDN, meanA, Wl2, DA,
                                       b2, bl2, nullptr, rbuf, N, HIDN);
  gcn_gather<<<nbWave, 256, 0, stream>>>(gbuf, rbuf, dinv, cites_off, deg_c,
                                         c_sorted, pbuf, N);
  // output projection
  dim3 gdim2((N + GBM - 1) / GBM, (DOUT + GBN - 1) / GBN);
  gemm_fused<<<gdim2, 256, 0, stream>>>(pbuf, linW, HIDN, nullptr, nullptr, 0,
                                        linb, nullptr, nullptr, out, N, DOUT);
}

// Round 2
// 1321.046 us; speedup vs baseline: 1.6843x; 1.6843x over previous
//
#include <hip/hip_runtime.h>

// HeteroGNN on MI355X — round 2: split-bf16 MFMA GEMMs (3-product hi/lo emulation).
//   - all GEMMs K=256 (x/p) with optional extra K=128 (mean) pass
//   - per-layer fused dual-output GEMM: g = (A@Wg)*dinv[row], r = A@Wr + mean@Wl + bias
//   - weights pre-transposed to [Npad][K] hi/lo bf16 planes; A pre-split to hi/lo planes
//   - global_load_lds(16B) staging, linear LDS dest + involution-XOR swizzled source/read

#define DP   256
#define DA   128
#define HIDN 256
#define DOUT 349

typedef unsigned short u16;
typedef __attribute__((ext_vector_type(8))) short bf16x8;
typedef __attribute__((ext_vector_type(4))) float f32x4;

__device__ __forceinline__ u16 bf16_rn(float x) {
  union { float f; unsigned u; } v; v.f = x;
  unsigned r = v.u + 0x7FFFu + ((v.u >> 16) & 1u);
  return (u16)(r >> 16);
}
__device__ __forceinline__ float bf16f(u16 h) {
  union { float f; unsigned u; } v; v.u = ((unsigned)h) << 16; return v.f;
}
__device__ __forceinline__ void split2(float x, u16& h, u16& l) {
  h = bf16_rn(x);
  l = bf16_rn(x - bf16f(h));
}

__device__ __forceinline__ void gload16(const void* g, void* lds) {
  __builtin_amdgcn_global_load_lds(
      (const __attribute__((address_space(1))) unsigned int*)g,
      (__attribute__((address_space(3))) unsigned int*)lds, 16, 0, 0);
}

// ---------------- histogram ----------------
__global__ void hist_kernel(const int* __restrict__ c_dst, const int* __restrict__ w_dst,
                            int* __restrict__ deg_c, int* __restrict__ cnt_w, int e) {
  int i = blockIdx.x * blockDim.x + threadIdx.x;
  if (i < e) {
    atomicAdd(&deg_c[c_dst[i]], 1);
    atomicAdd(&cnt_w[w_dst[i]], 1);
  }
}

// ---------------- exclusive scan ----------------
#define SCAN_TPB 256
#define SCAN_VPT 8
#define SCAN_TILE 2048

__global__ void scan_local(const int* __restrict__ in, int* __restrict__ out,
                           int* __restrict__ bsum, int n) {
  __shared__ int sdata[SCAN_TPB];
  int t = threadIdx.x;
  int base = blockIdx.x * SCAN_TILE + t * SCAN_VPT;
  int v[SCAN_VPT];
  int sum = 0;
#pragma unroll
  for (int j = 0; j < SCAN_VPT; ++j) {
    int idx = base + j;
    v[j] = (idx < n) ? in[idx] : 0;
    sum += v[j];
  }
  sdata[t] = sum;
  __syncthreads();
  for (int off = 1; off < SCAN_TPB; off <<= 1) {
    int x = (t >= off) ? sdata[t - off] : 0;
    __syncthreads();
    sdata[t] += x;
    __syncthreads();
  }
  int prefix = sdata[t] - sum;
  if (t == SCAN_TPB - 1) bsum[blockIdx.x] = sdata[t];
  int run = prefix;
#pragma unroll
  for (int j = 0; j < SCAN_VPT; ++j) {
    int idx = base + j;
    if (idx < n) out[idx] = run;
    run += v[j];
  }
}

__global__ void scan_spine(int* __restrict__ bsum, int nb) {
  __shared__ int sdata[256];
  int t = threadIdx.x;
  int v = (t < nb) ? bsum[t] : 0;
  sdata[t] = v;
  __syncthreads();
  for (int off = 1; off < 256; off <<= 1) {
    int x = (t >= off) ? sdata[t - off] : 0;
    __syncthreads();
    sdata[t] += x;
    __syncthreads();
  }
  if (t < nb) bsum[t] = sdata[t] - v;
}

__global__ void scan_add(int* __restrict__ out, const int* __restrict__ bsum, int n) {
  int add = bsum[blockIdx.x];
  int base = blockIdx.x * SCAN_TILE + threadIdx.x * SCAN_VPT;
#pragma unroll
  for (int j = 0; j < SCAN_VPT; ++j) {
    int idx = base + j;
    if (idx < n) out[idx] += add;
  }
}

// ---------------- CSR fill ----------------
__global__ void fill_csr(const int* __restrict__ c_src, const int* __restrict__ c_dst,
                         const int* __restrict__ w_src, const int* __restrict__ w_dst,
                         int* __restrict__ cur_c, int* __restrict__ cur_w,
                         int* __restrict__ c_sorted, int* __restrict__ w_sorted, int e) {
  int i = blockIdx.x * blockDim.x + threadIdx.x;
  if (i < e) {
    int d = c_dst[i];
    int pos = atomicAdd(&cur_c[d], 1);
    c_sorted[pos] = c_src[i];
    int d2 = w_dst[i];
    int pos2 = atomicAdd(&cur_w[d2], 1);
    w_sorted[pos2] = w_src[i];
  }
}

// ---------------- node prep: dinv + author-mean -> bf16 planes ----------------
__global__ void node_prep(const float* __restrict__ x_author,
                          const int* __restrict__ w_off, const int* __restrict__ w_cnt,
                          const int* __restrict__ w_sorted,
                          const int* __restrict__ deg_c,
                          u16* __restrict__ mhi, u16* __restrict__ mlo,
                          float* __restrict__ dinv, int n) {
  int wave = (blockIdx.x * blockDim.x + threadIdx.x) >> 6;
  int lane = threadIdx.x & 63;
  if (wave >= n) return;
  int d = wave;
  int start = w_off[d];
  int cnt = w_cnt[d];
  float ax = 0.f, ay = 0.f;
  const float2* xa = (const float2*)x_author;
  for (int j = 0; j < cnt; ++j) {
    int s = w_sorted[start + j];
    float2 v = xa[(size_t)s * (DA / 2) + lane];
    ax += v.x;
    ay += v.y;
  }
  float inv = 1.0f / (float)((cnt > 0) ? cnt : 1);
  float mx = ax * inv, my = ay * inv;
  union { u16 u[2]; unsigned v; } H, L;
  split2(mx, H.u[0], L.u[0]);
  split2(my, H.u[1], L.u[1]);
  ((unsigned*)mhi)[(size_t)d * (DA / 2) + lane] = H.v;
  ((unsigned*)mlo)[(size_t)d * (DA / 2) + lane] = L.v;
  if (lane == 0) dinv[d] = rsqrtf((float)(deg_c[d] + 1));
}

// ---------------- x_paper -> hi/lo bf16 planes ----------------
__global__ void conv_split(const float* __restrict__ x, u16* __restrict__ hi,
                           u16* __restrict__ lo, int n8) {
  int i = blockIdx.x * blockDim.x + threadIdx.x;
  if (i >= n8) return;
  const float4* xp = (const float4*)x;
  float4 v0 = xp[(size_t)i * 2];
  float4 v1 = xp[(size_t)i * 2 + 1];
  float vv[8] = {v0.x, v0.y, v0.z, v0.w, v1.x, v1.y, v1.z, v1.w};
  union { u16 u[8]; uint4 v; } H, L;
#pragma unroll
  for (int j = 0; j < 8; ++j) split2(vv[j], H.u[j], L.u[j]);
  ((uint4*)hi)[i] = H.v;
  ((uint4*)lo)[i] = L.v;
}

// ---------------- weight prep: W[K][N] -> Bt[2][Npad][K] hi/lo (transposed) -------
__global__ void prep_weight(const float* __restrict__ W, int K, int N, int Npad,
                            u16* __restrict__ Bt) {
  int idx = blockIdx.x * blockDim.x + threadIdx.x;
  int tot = Npad * K;
  if (idx >= tot) return;
  int n = idx / K, k = idx - n * K;
  float v = (n < N) ? W[(size_t)k * N + n] : 0.f;
  u16 h, l;
  split2(v, h, l);
  Bt[idx] = h;
  Bt[tot + idx] = l;
}

__global__ void add_bias(const float* __restrict__ a, const float* __restrict__ b,
                         float* __restrict__ o, int n) {
  int i = blockIdx.x * blockDim.x + threadIdx.x;
  if (i < n) o[i] = a[i] + b[i];
}

// ---------------- GCN gather + combine + relu -> bf16 planes ----------------
__global__ void gcn_gather(const float* __restrict__ g, const float* __restrict__ r,
                           const float* __restrict__ dinv,
                           const int* __restrict__ c_off, const int* __restrict__ c_cnt,
                           const int* __restrict__ c_sorted,
                           u16* __restrict__ phi, u16* __restrict__ plo, int n) {
  int wave = (blockIdx.x * blockDim.x + threadIdx.x) >> 6;
  int lane = threadIdx.x & 63;
  if (wave >= n) return;
  int d = wave;
  int start = c_off[d];
  int cnt = c_cnt[d];
  float a0 = 0.f, a1 = 0.f, a2 = 0.f, a3 = 0.f;
  const float4* G = (const float4*)g;
  for (int j = 0; j < cnt; ++j) {
    int s = c_sorted[start + j];
    float4 v = G[(size_t)s * (HIDN / 4) + lane];
    a0 += v.x; a1 += v.y; a2 += v.z; a3 += v.w;
  }
  float4 self = G[(size_t)d * (HIDN / 4) + lane];
  float sc = dinv[d];
  const float4* R = (const float4*)r;
  float4 rv = R[(size_t)d * (HIDN / 4) + lane];
  float o0 = fmaxf(fmaf(a0 + self.x, sc, rv.x), 0.f);
  float o1 = fmaxf(fmaf(a1 + self.y, sc, rv.y), 0.f);
  float o2 = fmaxf(fmaf(a2 + self.z, sc, rv.z), 0.f);
  float o3 = fmaxf(fmaf(a3 + self.w, sc, rv.w), 0.f);
  union { u16 u[4]; uint2 v; } H, L;
  split2(o0, H.u[0], L.u[0]);
  split2(o1, H.u[1], L.u[1]);
  split2(o2, H.u[2], L.u[2]);
  split2(o3, H.u[3], L.u[3]);
  ((uint2*)phi)[(size_t)d * (HIDN / 4) + lane] = H.v;
  ((uint2*)plo)[(size_t)d * (HIDN / 4) + lane] = L.v;
}

// ---------------- split-bf16 MFMA GEMM ----------------
// C tile 128x64, 4 waves (2x2), per-wave 64x32 = 4x2 frags of 16x16.
// A: [M][256] hi/lo bf16 planes. Optional mean pass: [M][128].
// B: Bt[2][Npad][K] (transposed, hi plane then lo plane).
// DUAL: G = (A@BtG)*dinv[row], R = A@BtR (+ mean@BtL) + biasR
// else: R = A@BtR + biasR   (N may be < padded tile; col-checked)
template <bool DUAL, bool HAS_MEAN>
__global__ __launch_bounds__(256) void gemm_mfma(
    const u16* __restrict__ Ahi, const u16* __restrict__ Alo,
    const u16* __restrict__ A2hi, const u16* __restrict__ A2lo,
    const u16* __restrict__ BtG, const u16* __restrict__ BtR,
    const u16* __restrict__ BtL, int bsG, int bsR, int bsL,
    const float* __restrict__ dinv, const float* __restrict__ biasR,
    float* __restrict__ G, float* __restrict__ R,
    int M, int N, int ldc) {
  __shared__ u16 Ah[128 * 32], Al[128 * 32];
  __shared__ u16 B0h[64 * 32], B0l[64 * 32];
  __shared__ u16 B1h[64 * 32], B1l[64 * 32];

  const int t = threadIdx.x;
  const int wid = t >> 6, lane = t & 63;
  const int wr = wid >> 1, wc = wid & 1;
  const int lrow = lane & 15, kslot = lane >> 4;
  const int jsw = kslot ^ (lrow & 3);
  const int gm = blockIdx.x * 128;
  const int gn = blockIdx.y * 64;

  // staging geometry: within a 16-row chunk, lane i -> row i/4, stored slot i&3,
  // fetching source k-slot (i&3)^(row&3)  (involution; read side XORs the same)
  const int s_r = lane >> 2;
  const int s_j = (lane & 3) ^ (s_r & 3);

  f32x4 accG[4][2], accR[4][2];
  const f32x4 z4 = {0.f, 0.f, 0.f, 0.f};
#pragma unroll
  for (int m = 0; m < 4; ++m)
#pragma unroll
    for (int n = 0; n < 2; ++n) { accG[m][n] = z4; accR[m][n] = z4; }

  // ---- phase 1: K = 256 over A ----
  for (int k0 = 0; k0 < 256; k0 += 32) {
    __syncthreads();
    {
      int c = wid * 2;
#pragma unroll
      for (int cc = 0; cc < 2; ++cc) {
        int rl = (c + cc) * 16 + s_r;
        int grow = gm + rl;
        grow = grow < M ? grow : M - 1;
        size_t go = (size_t)grow * 256 + (k0 + s_j * 8);
        gload16(Ahi + go, &Ah[(c + cc) * 512]);
        gload16(Alo + go, &Al[(c + cc) * 512]);
      }
    }
    {
      const u16* src = nullptr;
      u16* dst = nullptr;
      if (DUAL) {
        if (wid == 0)      { src = BtG;       dst = B0h; }
        else if (wid == 1) { src = BtG + bsG; dst = B0l; }
        else if (wid == 2) { src = BtR;       dst = B1h; }
        else               { src = BtR + bsR; dst = B1l; }
      } else {
        if (wid == 0)      { src = BtR;       dst = B0h; }
        else if (wid == 1) { src = BtR + bsR; dst = B0l; }
      }
      if (src) {
#pragma unroll
        for (int c = 0; c < 4; ++c) {
          int nl = c * 16 + s_r;
          size_t go = (size_t)(gn + nl) * 256 + (k0 + s_j * 8);
          gload16(src + go, dst + c * 512);
        }
      }
    }
    __syncthreads();

    bf16x8 ah[4], al[4];
    const int ab = (wr * 64 + lrow) * 32 + jsw * 8;
#pragma unroll
    for (int m = 0; m < 4; ++m) {
      ah[m] = *(const bf16x8*)&Ah[ab + m * 512];
      al[m] = *(const bf16x8*)&Al[ab + m * 512];
    }
    const int bb = (wc * 32 + lrow) * 32 + jsw * 8;
#pragma unroll
    for (int n = 0; n < 2; ++n) {
      int bo = bb + n * 512;
      bf16x8 b0h = *(const bf16x8*)&B0h[bo];
      bf16x8 b0l = *(const bf16x8*)&B0l[bo];
#pragma unroll
      for (int m = 0; m < 4; ++m) {
        if (DUAL) {
          accG[m][n] = __builtin_amdgcn_mfma_f32_16x16x32_bf16(ah[m], b0h, accG[m][n], 0, 0, 0);
          accG[m][n] = __builtin_amdgcn_mfma_f32_16x16x32_bf16(al[m], b0h, accG[m][n], 0, 0, 0);
          accG[m][n] = __builtin_amdgcn_mfma_f32_16x16x32_bf16(ah[m], b0l, accG[m][n], 0, 0, 0);
        } else {
          accR[m][n] = __builtin_amdgcn_mfma_f32_16x16x32_bf16(ah[m], b0h, accR[m][n], 0, 0, 0);
          accR[m][n] = __builtin_amdgcn_mfma_f32_16x16x32_bf16(al[m], b0h, accR[m][n], 0, 0, 0);
          accR[m][n] = __builtin_amdgcn_mfma_f32_16x16x32_bf16(ah[m], b0l, accR[m][n], 0, 0, 0);
        }
      }
      if (DUAL) {
        bf16x8 b1h = *(const bf16x8*)&B1h[bo];
        bf16x8 b1l = *(const bf16x8*)&B1l[bo];
#pragma unroll
        for (int m = 0; m < 4; ++m) {
          accR[m][n] = __builtin_amdgcn_mfma_f32_16x16x32_bf16(ah[m], b1h, accR[m][n], 0, 0, 0);
          accR[m][n] = __builtin_amdgcn_mfma_f32_16x16x32_bf16(al[m], b1h, accR[m][n], 0, 0, 0);
          accR[m][n] = __builtin_amdgcn_mfma_f32_16x16x32_bf16(ah[m], b1l, accR[m][n], 0, 0, 0);
        }
      }
    }
  }

  // ---- phase 2: K = 128 over mean (adds to accR) ----
  if (HAS_MEAN) {
    for (int k0 = 0; k0 < 128; k0 += 32) {
      __syncthreads();
      {
        int c = wid * 2;
#pragma unroll
        for (int cc = 0; cc < 2; ++cc) {
          int rl = (c + cc) * 16 + s_r;
          int grow = gm + rl;
          grow = grow < M ? grow : M - 1;
          size_t go = (size_t)grow * 128 + (k0 + s_j * 8);
          gload16(A2hi + go, &Ah[(c + cc) * 512]);
          gload16(A2lo + go, &Al[(c + cc) * 512]);
        }
      }
      {
        const u16* src = nullptr;
        u16* dst = nullptr;
        if (wid == 0)      { src = BtL;       dst = B0h; }
        else if (wid == 1) { src = BtL + bsL; dst = B0l; }
        if (src) {
#pragma unroll
          for (int c = 0; c < 4; ++c) {
            int nl = c * 16 + s_r;
            size_t go = (size_t)(gn + nl) * 128 + (k0 + s_j * 8);
            gload16(src + go, dst + c * 512);
          }
        }
      }
      __syncthreads();

      bf16x8 ah[4], al[4];
      const int ab = (wr * 64 + lrow) * 32 + jsw * 8;
#pragma unroll
      for (int m = 0; m < 4; ++m) {
        ah[m] = *(const bf16x8*)&Ah[ab + m * 512];
        al[m] = *(const bf16x8*)&Al[ab + m * 512];
      }
      const int bb = (wc * 32 + lrow) * 32 + jsw * 8;
#pragma unroll
      for (int n = 0; n < 2; ++n) {
        int bo = bb + n * 512;
        bf16x8 b0h = *(const bf16x8*)&B0h[bo];
        bf16x8 b0l = *(const bf16x8*)&B0l[bo];
#pragma unroll
        for (int m = 0; m < 4; ++m) {
          accR[m][n] = __builtin_amdgcn_mfma_f32_16x16x32_bf16(ah[m], b0h, accR[m][n], 0, 0, 0);
          accR[m][n] = __builtin_amdgcn_mfma_f32_16x16x32_bf16(al[m], b0h, accR[m][n], 0, 0, 0);
          accR[m][n] = __builtin_amdgcn_mfma_f32_16x16x32_bf16(ah[m], b0l, accR[m][n], 0, 0, 0);
        }
      }
    }
  }

  // ---- epilogue ----
  const int col0 = gn + wc * 32 + lrow;
  const int row00 = gm + wr * 64 + kslot * 4;
#pragma unroll
  for (int m = 0; m < 4; ++m) {
#pragma unroll
    for (int i = 0; i < 4; ++i) {
      int row = row00 + m * 16 + i;
      if (row < M) {
        float dv = 0.f;
        if (DUAL) dv = dinv[row];
#pragma unroll
        for (int n = 0; n < 2; ++n) {
          int col = col0 + n * 16;
          if (col < N) {
            size_t o = (size_t)row * ldc + col;
            if (DUAL) G[o] = accG[m][n][i] * dv;
            R[o] = accR[m][n][i] + biasR[col];
          }
        }
      }
    }
  }
}

// ---------------- launch ----------------
static inline size_t align_up(size_t x) { return (x + 255) & ~(size_t)255; }

extern "C" void kernel_launch(void* const* d_in, const int* in_sizes, int n_in,
                              void* d_out, int out_size, void* d_ws, size_t ws_size,
                              hipStream_t stream) {
  const float* x_paper  = (const float*)d_in[0];
  const float* x_author = (const float*)d_in[1];
  const int*   cites    = (const int*)d_in[2];
  const int*   w_src    = (const int*)d_in[3];
  const int*   w_dst    = (const int*)d_in[4];
  const float* W1  = (const float*)d_in[5];
  const float* b1  = (const float*)d_in[6];
  const float* Wl1 = (const float*)d_in[7];
  const float* bl1 = (const float*)d_in[8];
  const float* Wr1 = (const float*)d_in[9];
  const float* W2  = (const float*)d_in[10];
  const float* b2  = (const float*)d_in[11];
  const float* Wl2 = (const float*)d_in[12];
  const float* bl2 = (const float*)d_in[13];
  const float* Wr2 = (const float*)d_in[14];
  const float* linW = (const float*)d_in[15];
  const float* linb = (const float*)d_in[16];
  float* out = (float*)d_out;

  const int N = in_sizes[0] / DP;  // 100000
  const int E = in_sizes[3];       // 1000000
  const int* c_src = cites;
  const int* c_dst = cites + E;

  char* w = (char*)d_ws;
  size_t off = 0;
  auto alloc = [&](size_t bytes) -> void* {
    void* p = w + off;
    off = align_up(off + bytes);
    return p;
  };
  int* deg_c      = (int*)alloc((size_t)N * 4);
  int* cnt_w      = (int*)alloc((size_t)N * 4);
  int* cites_off  = (int*)alloc((size_t)N * 4);
  int* writes_off = (int*)alloc((size_t)N * 4);
  int* cur_c      = (int*)alloc((size_t)N * 4);
  int* cur_w      = (int*)alloc((size_t)N * 4);
  int* bsumA      = (int*)alloc(256 * 4);
  int* bsumB      = (int*)alloc(256 * 4);
  int* c_sorted   = (int*)alloc((size_t)E * 4);
  int* w_sorted   = (int*)alloc((size_t)E * 4);
  float* dinv     = (float*)alloc((size_t)N * 4);
  u16* m_hi       = (u16*)alloc((size_t)N * DA * 2);
  u16* m_lo       = (u16*)alloc((size_t)N * DA * 2);
  u16* p_hi       = (u16*)alloc((size_t)N * HIDN * 2);  // x_paper planes, then p planes
  u16* p_lo       = (u16*)alloc((size_t)N * HIDN * 2);
  float* gbuf     = (float*)alloc((size_t)N * HIDN * 4);
  float* rbuf     = (float*)alloc((size_t)N * HIDN * 4);
  const int bsW = 256 * 256, bsL = 256 * 128, bsLin = 384 * 256;
  u16* BtW1  = (u16*)alloc((size_t)2 * bsW * 2);
  u16* BtWr1 = (u16*)alloc((size_t)2 * bsW * 2);
  u16* BtW2  = (u16*)alloc((size_t)2 * bsW * 2);
  u16* BtWr2 = (u16*)alloc((size_t)2 * bsW * 2);
  u16* BtWl1 = (u16*)alloc((size_t)2 * bsL * 2);
  u16* BtWl2 = (u16*)alloc((size_t)2 * bsL * 2);
  u16* BtLin = (u16*)alloc((size_t)2 * bsLin * 2);
  float* biasR1 = (float*)alloc(HIDN * 4);
  float* biasR2 = (float*)alloc(HIDN * 4);
  (void)ws_size; (void)n_in; (void)out_size;

  hipMemsetAsync(deg_c, 0, (size_t)N * 4, stream);
  hipMemsetAsync(cnt_w, 0, (size_t)N * 4, stream);

  int nbE = (E + 255) / 256;
  hist_kernel<<<nbE, 256, 0, stream>>>(c_dst, w_dst, deg_c, cnt_w, E);

  int nsb = (N + SCAN_TILE - 1) / SCAN_TILE;
  scan_local<<<nsb, SCAN_TPB, 0, stream>>>(deg_c, cites_off, bsumA, N);
  scan_spine<<<1, 256, 0, stream>>>(bsumA, nsb);
  scan_add<<<nsb, SCAN_TPB, 0, stream>>>(cites_off, bsumA, N);
  scan_local<<<nsb, SCAN_TPB, 0, stream>>>(cnt_w, writes_off, bsumB, N);
  scan_spine<<<1, 256, 0, stream>>>(bsumB, nsb);
  scan_add<<<nsb, SCAN_TPB, 0, stream>>>(writes_off, bsumB, N);

  hipMemcpyAsync(cur_c, cites_off, (size_t)N * 4, hipMemcpyDeviceToDevice, stream);
  hipMemcpyAsync(cur_w, writes_off, (size_t)N * 4, hipMemcpyDeviceToDevice, stream);
  fill_csr<<<nbE, 256, 0, stream>>>(c_src, c_dst, w_src, w_dst, cur_c, cur_w,
                                    c_sorted, w_sorted, E);

  // input conversions (independent of CSR)
  int n8 = N * DP / 8;
  conv_split<<<(n8 + 255) / 256, 256, 0, stream>>>(x_paper, p_hi, p_lo, n8);
  prep_weight<<<(bsW + 255) / 256, 256, 0, stream>>>(W1, 256, 256, 256, BtW1);
  prep_weight<<<(bsW + 255) / 256, 256, 0, stream>>>(Wr1, 256, 256, 256, BtWr1);
  prep_weight<<<(bsW + 255) / 256, 256, 0, stream>>>(W2, 256, 256, 256, BtW2);
  prep_weight<<<(bsW + 255) / 256, 256, 0, stream>>>(Wr2, 256, 256, 256, BtWr2);
  prep_weight<<<(bsL + 255) / 256, 256, 0, stream>>>(Wl1, 128, 256, 256, BtWl1);
  prep_weight<<<(bsL + 255) / 256, 256, 0, stream>>>(Wl2, 128, 256, 256, BtWl2);
  prep_weight<<<(bsLin + 255) / 256, 256, 0, stream>>>(linW, 256, DOUT, 384, BtLin);
  add_bias<<<1, 256, 0, stream>>>(b1, bl1, biasR1, HIDN);
  add_bias<<<1, 256, 0, stream>>>(b2, bl2, biasR2, HIDN);

  int nbWave = (N * 64 + 255) / 256;
  node_prep<<<nbWave, 256, 0, stream>>>(x_author, writes_off, cnt_w, w_sorted,
                                        deg_c, m_hi, m_lo, dinv, N);

  dim3 gdim((N + 127) / 128, 4);
  // layer 1
  gemm_mfma<true, true><<<gdim, 256, 0, stream>>>(
      p_hi, p_lo, m_hi, m_lo, BtW1, BtWr1, BtWl1, bsW, bsW, bsL,
      dinv, biasR1, gbuf, rbuf, N, HIDN, HIDN);
  gcn_gather<<<nbWave, 256, 0, stream>>>(gbuf, rbuf, dinv, cites_off, deg_c,
                                         c_sorted, p_hi, p_lo, N);
  // layer 2
  gemm_mfma<true, true><<<gdim, 256, 0, stream>>>(
      p_hi, p_lo, m_hi, m_lo, BtW2, BtWr2, BtWl2, bsW, bsW, bsL,
      dinv, biasR2, gbuf, rbuf, N, HIDN, HIDN);
  gcn_gather<<<nbWave, 256, 0, stream>>>(gbuf, rbuf, dinv, cites_off, deg_c,
                                         c_sorted, p_hi, p_lo, N);
  // output projection
  dim3 gdim2((N + 127) / 128, 6);
  gemm_mfma<false, false><<<gdim2, 256, 0, stream>>>(
      p_hi, p_lo, nullptr, nullptr, nullptr, BtLin, nullptr, 0, bsLin, 0,
      nullptr, linb, nullptr, out, N, DOUT, DOUT);
}

// Round 3
// 1234.300 us; speedup vs baseline: 1.8027x; 1.0703x over previous
//
#include <hip/hip_runtime.h>

// HeteroGNN on MI355X — round 3: dbuf-pipelined split-bf16 MFMA GEMM,
// conflict-free LDS swizzle, XCD-chunked block swizzle, shfl-batched gathers.

#define DP   256
#define DA   128
#define HIDN 256
#define DOUT 349

typedef unsigned short u16;
typedef __attribute__((ext_vector_type(8))) short bf16x8;
typedef __attribute__((ext_vector_type(4))) float f32x4;

__device__ __forceinline__ u16 bf16_rn(float x) {
  union { float f; unsigned u; } v; v.f = x;
  unsigned r = v.u + 0x7FFFu + ((v.u >> 16) & 1u);
  return (u16)(r >> 16);
}
__device__ __forceinline__ float bf16f(u16 h) {
  union { float f; unsigned u; } v; v.u = ((unsigned)h) << 16; return v.f;
}
__device__ __forceinline__ void split2(float x, u16& h, u16& l) {
  h = bf16_rn(x);
  l = bf16_rn(x - bf16f(h));
}

__device__ __forceinline__ void gload16(const void* g, void* lds) {
  __builtin_amdgcn_global_load_lds(
      (const __attribute__((address_space(1))) unsigned int*)g,
      (__attribute__((address_space(3))) unsigned int*)lds, 16, 0, 0);
}

// ---------------- histogram ----------------
__global__ void hist_kernel(const int* __restrict__ c_dst, const int* __restrict__ w_dst,
                            int* __restrict__ deg_c, int* __restrict__ cnt_w, int e) {
  int i = blockIdx.x * blockDim.x + threadIdx.x;
  if (i < e) {
    atomicAdd(&deg_c[c_dst[i]], 1);
    atomicAdd(&cnt_w[w_dst[i]], 1);
  }
}

// ---------------- exclusive scan ----------------
#define SCAN_TPB 256
#define SCAN_VPT 8
#define SCAN_TILE 2048

__global__ void scan_local(const int* __restrict__ in, int* __restrict__ out,
                           int* __restrict__ bsum, int n) {
  __shared__ int sdata[SCAN_TPB];
  int t = threadIdx.x;
  int base = blockIdx.x * SCAN_TILE + t * SCAN_VPT;
  int v[SCAN_VPT];
  int sum = 0;
#pragma unroll
  for (int j = 0; j < SCAN_VPT; ++j) {
    int idx = base + j;
    v[j] = (idx < n) ? in[idx] : 0;
    sum += v[j];
  }
  sdata[t] = sum;
  __syncthreads();
  for (int off = 1; off < SCAN_TPB; off <<= 1) {
    int x = (t >= off) ? sdata[t - off] : 0;
    __syncthreads();
    sdata[t] += x;
    __syncthreads();
  }
  int prefix = sdata[t] - sum;
  if (t == SCAN_TPB - 1) bsum[blockIdx.x] = sdata[t];
  int run = prefix;
#pragma unroll
  for (int j = 0; j < SCAN_VPT; ++j) {
    int idx = base + j;
    if (idx < n) out[idx] = run;
    run += v[j];
  }
}

__global__ void scan_spine(int* __restrict__ bsum, int nb) {
  __shared__ int sdata[256];
  int t = threadIdx.x;
  int v = (t < nb) ? bsum[t] : 0;
  sdata[t] = v;
  __syncthreads();
  for (int off = 1; off < 256; off <<= 1) {
    int x = (t >= off) ? sdata[t - off] : 0;
    __syncthreads();
    sdata[t] += x;
    __syncthreads();
  }
  if (t < nb) bsum[t] = sdata[t] - v;
}

__global__ void scan_add(int* __restrict__ out, const int* __restrict__ bsum, int n) {
  int add = bsum[blockIdx.x];
  int base = blockIdx.x * SCAN_TILE + threadIdx.x * SCAN_VPT;
#pragma unroll
  for (int j = 0; j < SCAN_VPT; ++j) {
    int idx = base + j;
    if (idx < n) out[idx] += add;
  }
}

// ---------------- CSR fill ----------------
__global__ void fill_csr(const int* __restrict__ c_src, const int* __restrict__ c_dst,
                         const int* __restrict__ w_src, const int* __restrict__ w_dst,
                         int* __restrict__ cur_c, int* __restrict__ cur_w,
                         int* __restrict__ c_sorted, int* __restrict__ w_sorted, int e) {
  int i = blockIdx.x * blockDim.x + threadIdx.x;
  if (i < e) {
    int d = c_dst[i];
    int pos = atomicAdd(&cur_c[d], 1);
    c_sorted[pos] = c_src[i];
    int d2 = w_dst[i];
    int pos2 = atomicAdd(&cur_w[d2], 1);
    w_sorted[pos2] = w_src[i];
  }
}

// ---------------- node prep: dinv + author-mean -> bf16 planes ----------------
__global__ void node_prep(const float* __restrict__ x_author,
                          const int* __restrict__ w_off, const int* __restrict__ w_cnt,
                          const int* __restrict__ w_sorted,
                          const int* __restrict__ deg_c,
                          u16* __restrict__ mhi, u16* __restrict__ mlo,
                          float* __restrict__ dinv, int n) {
  int wave = (blockIdx.x * blockDim.x + threadIdx.x) >> 6;
  int lane = threadIdx.x & 63;
  if (wave >= n) return;
  int d = wave;
  int start = w_off[d];
  int cnt = w_cnt[d];
  float ax = 0.f, ay = 0.f;
  const float2* xa = (const float2*)x_author;
  for (int j0 = 0; j0 < cnt; j0 += 64) {
    int nn = cnt - j0; nn = nn < 64 ? nn : 64;
    int sl = (j0 + lane < cnt) ? w_sorted[start + j0 + lane] : 0;
    for (int jj = 0; jj < nn; ++jj) {
      int s = __shfl(sl, jj);
      float2 v = xa[(size_t)s * (DA / 2) + lane];
      ax += v.x;
      ay += v.y;
    }
  }
  float inv = 1.0f / (float)((cnt > 0) ? cnt : 1);
  float mx = ax * inv, my = ay * inv;
  union { u16 u[2]; unsigned v; } H, L;
  split2(mx, H.u[0], L.u[0]);
  split2(my, H.u[1], L.u[1]);
  ((unsigned*)mhi)[(size_t)d * (DA / 2) + lane] = H.v;
  ((unsigned*)mlo)[(size_t)d * (DA / 2) + lane] = L.v;
  if (lane == 0) dinv[d] = rsqrtf((float)(deg_c[d] + 1));
}

// ---------------- x_paper -> hi/lo bf16 planes ----------------
__global__ void conv_split(const float* __restrict__ x, u16* __restrict__ hi,
                           u16* __restrict__ lo, int n8) {
  int i = blockIdx.x * blockDim.x + threadIdx.x;
  if (i >= n8) return;
  const float4* xp = (const float4*)x;
  float4 v0 = xp[(size_t)i * 2];
  float4 v1 = xp[(size_t)i * 2 + 1];
  float vv[8] = {v0.x, v0.y, v0.z, v0.w, v1.x, v1.y, v1.z, v1.w};
  union { u16 u[8]; uint4 v; } H, L;
#pragma unroll
  for (int j = 0; j < 8; ++j) split2(vv[j], H.u[j], L.u[j]);
  ((uint4*)hi)[i] = H.v;
  ((uint4*)lo)[i] = L.v;
}

// ---------------- weight prep: W[K][N] -> Bt[2][Npad][K] hi/lo ----------------
__global__ void prep_weight(const float* __restrict__ W, int K, int N, int Npad,
                            u16* __restrict__ Bt) {
  int idx = blockIdx.x * blockDim.x + threadIdx.x;
  int tot = Npad * K;
  if (idx >= tot) return;
  int n = idx / K, k = idx - n * K;
  float v = (n < N) ? W[(size_t)k * N + n] : 0.f;
  u16 h, l;
  split2(v, h, l);
  Bt[idx] = h;
  Bt[tot + idx] = l;
}

__global__ void add_bias(const float* __restrict__ a, const float* __restrict__ b,
                         float* __restrict__ o, int n) {
  int i = blockIdx.x * blockDim.x + threadIdx.x;
  if (i < n) o[i] = a[i] + b[i];
}

// ---------------- GCN gather + combine + relu -> bf16 planes ----------------
__global__ void gcn_gather(const float* __restrict__ g, const float* __restrict__ r,
                           const float* __restrict__ dinv,
                           const int* __restrict__ c_off, const int* __restrict__ c_cnt,
                           const int* __restrict__ c_sorted,
                           u16* __restrict__ phi, u16* __restrict__ plo, int n) {
  int wave = (blockIdx.x * blockDim.x + threadIdx.x) >> 6;
  int lane = threadIdx.x & 63;
  if (wave >= n) return;
  int d = wave;
  int start = c_off[d];
  int cnt = c_cnt[d];
  float a0 = 0.f, a1 = 0.f, a2 = 0.f, a3 = 0.f;
  const float4* G = (const float4*)g;
  for (int j0 = 0; j0 < cnt; j0 += 64) {
    int nn = cnt - j0; nn = nn < 64 ? nn : 64;
    int sl = (j0 + lane < cnt) ? c_sorted[start + j0 + lane] : 0;
    for (int jj = 0; jj < nn; ++jj) {
      int s = __shfl(sl, jj);
      float4 v = G[(size_t)s * (HIDN / 4) + lane];
      a0 += v.x; a1 += v.y; a2 += v.z; a3 += v.w;
    }
  }
  float4 self = G[(size_t)d * (HIDN / 4) + lane];
  float sc = dinv[d];
  const float4* R = (const float4*)r;
  float4 rv = R[(size_t)d * (HIDN / 4) + lane];
  float o0 = fmaxf(fmaf(a0 + self.x, sc, rv.x), 0.f);
  float o1 = fmaxf(fmaf(a1 + self.y, sc, rv.y), 0.f);
  float o2 = fmaxf(fmaf(a2 + self.z, sc, rv.z), 0.f);
  float o3 = fmaxf(fmaf(a3 + self.w, sc, rv.w), 0.f);
  union { u16 u[4]; uint2 v; } H, L;
  split2(o0, H.u[0], L.u[0]);
  split2(o1, H.u[1], L.u[1]);
  split2(o2, H.u[2], L.u[2]);
  split2(o3, H.u[3], L.u[3]);
  ((uint2*)phi)[(size_t)d * (HIDN / 4) + lane] = H.v;
  ((uint2*)plo)[(size_t)d * (HIDN / 4) + lane] = L.v;
}

// ---------------- split-bf16 MFMA GEMM, double-buffered 2-phase pipeline ------
// C tile 128x64, 4 waves (2x2), per-wave 64x32 = 4x2 frags of 16x16.
// LDS swizzle: slot' = slot ^ ((row>>1)&3)  (involution; applied to global src
// at stage time and to the read slot — LDS dest stays linear for gload_lds).
// Block swizzle: bijective XCD chunk (m204), column-tile-fastest within chunk.
template <bool DUAL, bool HAS_MEAN, int GY>
__global__ __launch_bounds__(256) void gemm_mfma(
    const u16* __restrict__ Ahi, const u16* __restrict__ Alo,
    const u16* __restrict__ A2hi, const u16* __restrict__ A2lo,
    const u16* __restrict__ BtG, const u16* __restrict__ BtR,
    const u16* __restrict__ BtL, int bsG, int bsR, int bsL,
    const float* __restrict__ dinv, const float* __restrict__ biasR,
    float* __restrict__ G, float* __restrict__ R,
    int M, int N, int ldc) {
  __shared__ u16 Ah[2][128 * 32], Al[2][128 * 32];
  __shared__ u16 B0h[2][64 * 32], B0l[2][64 * 32];
  __shared__ u16 B1h[2][64 * 32], B1l[2][64 * 32];

  const int t = threadIdx.x;
  const int wid = t >> 6, lane = t & 63;
  const int wr = wid >> 1, wc = wid & 1;
  const int lrow = lane & 15, kslot = lane >> 4;
  const int jsw = kslot ^ ((lrow >> 1) & 3);

  // bijective XCD-chunked block swizzle (m204)
  const int nb = gridDim.x;
  const int q = nb >> 3, r = nb & 7;
  const int xcd = blockIdx.x & 7, pos = blockIdx.x >> 3;
  const int lin = (xcd < r ? xcd * (q + 1) : r * (q + 1) + (xcd - r) * q) + pos;
  const int bx = lin / GY, by = lin - bx * GY;
  const int gm = bx * 128;
  const int gn = by * 64;

  // staging source swizzle: lane -> (row = lane>>2, slot = lane&3)
  const int s_r = lane >> 2;
  const int s_j = (lane & 3) ^ ((s_r >> 1) & 3);

  f32x4 accG[4][2], accR[4][2];
  const f32x4 z4 = {0.f, 0.f, 0.f, 0.f};
#pragma unroll
  for (int m = 0; m < 4; ++m)
#pragma unroll
    for (int n = 0; n < 2; ++n) { accG[m][n] = z4; accR[m][n] = z4; }

  const int NT = HAS_MEAN ? 12 : 8;

  auto STAGE = [&](int tt, int half) {
    if (!HAS_MEAN || tt < 8) {
      const int k0 = tt * 32;
      // A: each wave stages 2 chunks of 16 rows
      {
        int c = wid * 2;
#pragma unroll
        for (int cc = 0; cc < 2; ++cc) {
          int grow = gm + (c + cc) * 16 + s_r;
          grow = grow < M ? grow : M - 1;
          size_t go = (size_t)grow * 256 + (k0 + s_j * 8);
          gload16(Ahi + go, &Ah[half][(c + cc) * 512]);
          gload16(Alo + go, &Al[half][(c + cc) * 512]);
        }
      }
      const u16* src = nullptr;
      u16* dst = nullptr;
      if (DUAL) {
        if (wid == 0)      { src = BtG;       dst = B0h[half]; }
        else if (wid == 1) { src = BtG + bsG; dst = B0l[half]; }
        else if (wid == 2) { src = BtR;       dst = B1h[half]; }
        else               { src = BtR + bsR; dst = B1l[half]; }
      } else {
        if (wid == 0)      { src = BtR;       dst = B0h[half]; }
        else if (wid == 1) { src = BtR + bsR; dst = B0l[half]; }
      }
      if (src) {
#pragma unroll
        for (int c = 0; c < 4; ++c) {
          size_t go = (size_t)(gn + c * 16 + s_r) * 256 + (k0 + s_j * 8);
          gload16(src + go, dst + c * 512);
        }
      }
    } else {
      const int k0 = (tt - 8) * 32;
      {
        int c = wid * 2;
#pragma unroll
        for (int cc = 0; cc < 2; ++cc) {
          int grow = gm + (c + cc) * 16 + s_r;
          grow = grow < M ? grow : M - 1;
          size_t go = (size_t)grow * 128 + (k0 + s_j * 8);
          gload16(A2hi + go, &Ah[half][(c + cc) * 512]);
          gload16(A2lo + go, &Al[half][(c + cc) * 512]);
        }
      }
      const u16* src = nullptr;
      u16* dst = nullptr;
      if (wid == 0)      { src = BtL;       dst = B0h[half]; }
      else if (wid == 1) { src = BtL + bsL; dst = B0l[half]; }
      if (src) {
#pragma unroll
        for (int c = 0; c < 4; ++c) {
          size_t go = (size_t)(gn + c * 16 + s_r) * 128 + (k0 + s_j * 8);
          gload16(src + go, dst + c * 512);
        }
      }
    }
  };

  STAGE(0, 0);
  __syncthreads();  // drains vmcnt(0): buf0 ready

  for (int tt = 0; tt < NT; ++tt) {
    const int half = tt & 1;
    if (tt + 1 < NT) STAGE(tt + 1, half ^ 1);  // issue next-tile loads (overlap)

    const bool p2 = HAS_MEAN && (tt >= 8);
    bf16x8 ah[4], al[4];
    const int abase = (wr * 64 + lrow) * 32 + jsw * 8;
#pragma unroll
    for (int m = 0; m < 4; ++m) {
      ah[m] = *(const bf16x8*)&Ah[half][abase + m * 512];
      al[m] = *(const bf16x8*)&Al[half][abase + m * 512];
    }
    const int bbase = (wc * 32 + lrow) * 32 + jsw * 8;
#pragma unroll
    for (int n = 0; n < 2; ++n) {
      const int bo = bbase + n * 512;
      bf16x8 b0h = *(const bf16x8*)&B0h[half][bo];
      bf16x8 b0l = *(const bf16x8*)&B0l[half][bo];
      if (!p2) {
#pragma unroll
        for (int m = 0; m < 4; ++m) {
          if (DUAL) {
            accG[m][n] = __builtin_amdgcn_mfma_f32_16x16x32_bf16(ah[m], b0h, accG[m][n], 0, 0, 0);
            accG[m][n] = __builtin_amdgcn_mfma_f32_16x16x32_bf16(al[m], b0h, accG[m][n], 0, 0, 0);
            accG[m][n] = __builtin_amdgcn_mfma_f32_16x16x32_bf16(ah[m], b0l, accG[m][n], 0, 0, 0);
          } else {
            accR[m][n] = __builtin_amdgcn_mfma_f32_16x16x32_bf16(ah[m], b0h, accR[m][n], 0, 0, 0);
            accR[m][n] = __builtin_amdgcn_mfma_f32_16x16x32_bf16(al[m], b0h, accR[m][n], 0, 0, 0);
            accR[m][n] = __builtin_amdgcn_mfma_f32_16x16x32_bf16(ah[m], b0l, accR[m][n], 0, 0, 0);
          }
        }
        if (DUAL) {
          bf16x8 b1h = *(const bf16x8*)&B1h[half][bo];
          bf16x8 b1l = *(const bf16x8*)&B1l[half][bo];
#pragma unroll
          for (int m = 0; m < 4; ++m) {
            accR[m][n] = __builtin_amdgcn_mfma_f32_16x16x32_bf16(ah[m], b1h, accR[m][n], 0, 0, 0);
            accR[m][n] = __builtin_amdgcn_mfma_f32_16x16x32_bf16(al[m], b1h, accR[m][n], 0, 0, 0);
            accR[m][n] = __builtin_amdgcn_mfma_f32_16x16x32_bf16(ah[m], b1l, accR[m][n], 0, 0, 0);
          }
        }
      } else {
#pragma unroll
        for (int m = 0; m < 4; ++m) {
          accR[m][n] = __builtin_amdgcn_mfma_f32_16x16x32_bf16(ah[m], b0h, accR[m][n], 0, 0, 0);
          accR[m][n] = __builtin_amdgcn_mfma_f32_16x16x32_bf16(al[m], b0h, accR[m][n], 0, 0, 0);
          accR[m][n] = __builtin_amdgcn_mfma_f32_16x16x32_bf16(ah[m], b0l, accR[m][n], 0, 0, 0);
        }
      }
    }
    __syncthreads();  // drains vmcnt(0): next buffer ready; protects buffer reuse
  }

  // ---- epilogue ----
  const int col0 = gn + wc * 32 + lrow;
  const int row00 = gm + wr * 64 + kslot * 4;
#pragma unroll
  for (int m = 0; m < 4; ++m) {
#pragma unroll
    for (int i = 0; i < 4; ++i) {
      int row = row00 + m * 16 + i;
      if (row < M) {
        float dv = 0.f;
        if (DUAL) dv = dinv[row];
#pragma unroll
        for (int n = 0; n < 2; ++n) {
          int col = col0 + n * 16;
          if (col < N) {
            size_t o = (size_t)row * ldc + col;
            if (DUAL) G[o] = accG[m][n][i] * dv;
            R[o] = accR[m][n][i] + biasR[col];
          }
        }
      }
    }
  }
}

// ---------------- launch ----------------
static inline size_t align_up(size_t x) { return (x + 255) & ~(size_t)255; }

extern "C" void kernel_launch(void* const* d_in, const int* in_sizes, int n_in,
                              void* d_out, int out_size, void* d_ws, size_t ws_size,
                              hipStream_t stream) {
  const float* x_paper  = (const float*)d_in[0];
  const float* x_author = (const float*)d_in[1];
  const int*   cites    = (const int*)d_in[2];
  const int*   w_src    = (const int*)d_in[3];
  const int*   w_dst    = (const int*)d_in[4];
  const float* W1  = (const float*)d_in[5];
  const float* b1  = (const float*)d_in[6];
  const float* Wl1 = (const float*)d_in[7];
  const float* bl1 = (const float*)d_in[8];
  const float* Wr1 = (const float*)d_in[9];
  const float* W2  = (const float*)d_in[10];
  const float* b2  = (const float*)d_in[11];
  const float* Wl2 = (const float*)d_in[12];
  const float* bl2 = (const float*)d_in[13];
  const float* Wr2 = (const float*)d_in[14];
  const float* linW = (const float*)d_in[15];
  const float* linb = (const float*)d_in[16];
  float* out = (float*)d_out;

  const int N = in_sizes[0] / DP;  // 100000
  const int E = in_sizes[3];       // 1000000
  const int* c_src = cites;
  const int* c_dst = cites + E;

  char* w = (char*)d_ws;
  size_t off = 0;
  auto alloc = [&](size_t bytes) -> void* {
    void* p = w + off;
    off = align_up(off + bytes);
    return p;
  };
  int* deg_c      = (int*)alloc((size_t)N * 4);
  int* cnt_w      = (int*)alloc((size_t)N * 4);
  int* cites_off  = (int*)alloc((size_t)N * 4);
  int* writes_off = (int*)alloc((size_t)N * 4);
  int* cur_c      = (int*)alloc((size_t)N * 4);
  int* cur_w      = (int*)alloc((size_t)N * 4);
  int* bsumA      = (int*)alloc(256 * 4);
  int* bsumB      = (int*)alloc(256 * 4);
  int* c_sorted   = (int*)alloc((size_t)E * 4);
  int* w_sorted   = (int*)alloc((size_t)E * 4);
  float* dinv     = (float*)alloc((size_t)N * 4);
  u16* m_hi       = (u16*)alloc((size_t)N * DA * 2);
  u16* m_lo       = (u16*)alloc((size_t)N * DA * 2);
  u16* p_hi       = (u16*)alloc((size_t)N * HIDN * 2);
  u16* p_lo       = (u16*)alloc((size_t)N * HIDN * 2);
  float* gbuf     = (float*)alloc((size_t)N * HIDN * 4);
  float* rbuf     = (float*)alloc((size_t)N * HIDN * 4);
  const int bsW = 256 * 256, bsL = 256 * 128, bsLin = 384 * 256;
  u16* BtW1  = (u16*)alloc((size_t)2 * bsW * 2);
  u16* BtWr1 = (u16*)alloc((size_t)2 * bsW * 2);
  u16* BtW2  = (u16*)alloc((size_t)2 * bsW * 2);
  u16* BtWr2 = (u16*)alloc((size_t)2 * bsW * 2);
  u16* BtWl1 = (u16*)alloc((size_t)2 * bsL * 2);
  u16* BtWl2 = (u16*)alloc((size_t)2 * bsL * 2);
  u16* BtLin = (u16*)alloc((size_t)2 * bsLin * 2);
  float* biasR1 = (float*)alloc(HIDN * 4);
  float* biasR2 = (float*)alloc(HIDN * 4);
  (void)ws_size; (void)n_in; (void)out_size;

  hipMemsetAsync(deg_c, 0, (size_t)N * 4, stream);
  hipMemsetAsync(cnt_w, 0, (size_t)N * 4, stream);

  int nbE = (E + 255) / 256;
  hist_kernel<<<nbE, 256, 0, stream>>>(c_dst, w_dst, deg_c, cnt_w, E);

  int nsb = (N + SCAN_TILE - 1) / SCAN_TILE;
  scan_local<<<nsb, SCAN_TPB, 0, stream>>>(deg_c, cites_off, bsumA, N);
  scan_spine<<<1, 256, 0, stream>>>(bsumA, nsb);
  scan_add<<<nsb, SCAN_TPB, 0, stream>>>(cites_off, bsumA, N);
  scan_local<<<nsb, SCAN_TPB, 0, stream>>>(cnt_w, writes_off, bsumB, N);
  scan_spine<<<1, 256, 0, stream>>>(bsumB, nsb);
  scan_add<<<nsb, SCAN_TPB, 0, stream>>>(writes_off, bsumB, N);

  hipMemcpyAsync(cur_c, cites_off, (size_t)N * 4, hipMemcpyDeviceToDevice, stream);
  hipMemcpyAsync(cur_w, writes_off, (size_t)N * 4, hipMemcpyDeviceToDevice, stream);
  fill_csr<<<nbE, 256, 0, stream>>>(c_src, c_dst, w_src, w_dst, cur_c, cur_w,
                                    c_sorted, w_sorted, E);

  int n8 = N * DP / 8;
  conv_split<<<(n8 + 255) / 256, 256, 0, stream>>>(x_paper, p_hi, p_lo, n8);
  prep_weight<<<(bsW + 255) / 256, 256, 0, stream>>>(W1, 256, 256, 256, BtW1);
  prep_weight<<<(bsW + 255) / 256, 256, 0, stream>>>(Wr1, 256, 256, 256, BtWr1);
  prep_weight<<<(bsW + 255) / 256, 256, 0, stream>>>(W2, 256, 256, 256, BtW2);
  prep_weight<<<(bsW + 255) / 256, 256, 0, stream>>>(Wr2, 256, 256, 256, BtWr2);
  prep_weight<<<(bsL + 255) / 256, 256, 0, stream>>>(Wl1, 128, 256, 256, BtWl1);
  prep_weight<<<(bsL + 255) / 256, 256, 0, stream>>>(Wl2, 128, 256, 256, BtWl2);
  prep_weight<<<(bsLin + 255) / 256, 256, 0, stream>>>(linW, 256, DOUT, 384, BtLin);
  add_bias<<<1, 256, 0, stream>>>(b1, bl1, biasR1, HIDN);
  add_bias<<<1, 256, 0, stream>>>(b2, bl2, biasR2, HIDN);

  int nbWave = (N * 64 + 255) / 256;
  node_prep<<<nbWave, 256, 0, stream>>>(x_author, writes_off, cnt_w, w_sorted,
                                        deg_c, m_hi, m_lo, dinv, N);

  const int GX = (N + 127) / 128;  // 782
  // layer 1
  gemm_mfma<true, true, 4><<<GX * 4, 256, 0, stream>>>(
      p_hi, p_lo, m_hi, m_lo, BtW1, BtWr1, BtWl1, bsW, bsW, bsL,
      dinv, biasR1, gbuf, rbuf, N, HIDN, HIDN);
  gcn_gather<<<nbWave, 256, 0, stream>>>(gbuf, rbuf, dinv, cites_off, deg_c,
                                         c_sorted, p_hi, p_lo, N);
  // layer 2
  gemm_mfma<true, true, 4><<<GX * 4, 256, 0, stream>>>(
      p_hi, p_lo, m_hi, m_lo, BtW2, BtWr2, BtWl2, bsW, bsW, bsL,
      dinv, biasR2, gbuf, rbuf, N, HIDN, HIDN);
  gcn_gather<<<nbWave, 256, 0, stream>>>(gbuf, rbuf, dinv, cites_off, deg_c,
                                         c_sorted, p_hi, p_lo, N);
  // output projection
  gemm_mfma<false, false, 6><<<GX * 6, 256, 0, stream>>>(
      p_hi, p_lo, nullptr, nullptr, nullptr, BtLin, nullptr, 0, bsLin, 0,
      nullptr, linb, nullptr, out, N, DOUT, DOUT);
}